// Round 8
// baseline (407.637 us; speedup 1.0000x reference)
//
#include <hip/hip_runtime.h>

#define NN 50000
#define NE 400000
#define NBLK 196   // ceil(NN/256)

using short8 = __attribute__((ext_vector_type(8))) short;
using f32x4  = __attribute__((ext_vector_type(4))) float;
using f32x2  = __attribute__((ext_vector_type(2))) float;
using u16x2  = __attribute__((ext_vector_type(2))) unsigned short;
using u16x4  = __attribute__((ext_vector_type(4))) unsigned short;

__device__ __forceinline__ unsigned short f2b(float f) {
    union { float f; unsigned int u; } x; x.f = f;
    unsigned int u = x.u;
    u += 0x7fffu + ((u >> 16) & 1u);   // RNE
    return (unsigned short)(u >> 16);
}
__device__ __forceinline__ float b2f(unsigned short u) {
    union { unsigned int u; float f; } x; x.u = ((unsigned int)u) << 16;
    return x.f;
}

#define SWZ(b, row) ((b) ^ (((row) & 7) << 4))

// async global->LDS, 16B per lane; LDS dest must be wave-uniform-base + lane*16
__device__ __forceinline__ void gload16(const void* g, void* l) {
    __builtin_amdgcn_global_load_lds(
        (const __attribute__((address_space(1))) void*)g,
        (__attribute__((address_space(3))) void*)l, 16, 0, 0);
}

// ---------------- CSR build ----------------
__global__ __launch_bounds__(256) void zero2_k(int* a, int* b) {
    int i = blockIdx.x * 256 + threadIdx.x;
    if (i < NN) { a[i] = 0; b[i] = 0; }
}
__global__ __launch_bounds__(256) void count_k(const int* __restrict__ dst, int* __restrict__ indeg) {
    int e = blockIdx.x * 256 + threadIdx.x;
    if (e < NE) atomicAdd(&indeg[dst[e]], 1);
}
__global__ __launch_bounds__(256) void scan1_k(const int* __restrict__ indeg, int* __restrict__ tmp,
                                               int* __restrict__ bsum) {
    __shared__ int s[256];
    int t = threadIdx.x, i = blockIdx.x * 256 + t;
    int v = (i < NN) ? indeg[i] : 0;
    s[t] = v; __syncthreads();
    for (int off = 1; off < 256; off <<= 1) {
        int x = (t >= off) ? s[t - off] : 0;
        __syncthreads();
        s[t] += x;
        __syncthreads();
    }
    if (i < NN) tmp[i] = s[t];
    if (t == 255) bsum[blockIdx.x] = s[255];
}
__global__ __launch_bounds__(256) void scan2_k(const int* __restrict__ bsum, int* __restrict__ boff) {
    __shared__ int s[256];
    int t = threadIdx.x;
    int v = (t < NBLK) ? bsum[t] : 0;
    s[t] = v; __syncthreads();
    for (int off = 1; off < 256; off <<= 1) {
        int x = (t >= off) ? s[t - off] : 0;
        __syncthreads();
        s[t] += x;
        __syncthreads();
    }
    if (t < NBLK) boff[t] = s[t] - v;   // exclusive
}
__global__ __launch_bounds__(256) void scan3_k(const int* __restrict__ tmp, const int* __restrict__ indeg,
                                               const int* __restrict__ boff, int* __restrict__ rowptr,
                                               float* __restrict__ dinv) {
    int i = blockIdx.x * 256 + threadIdx.x;
    if (i < NN) {
        rowptr[i] = tmp[i] - indeg[i] + boff[i >> 8];
        dinv[i] = rsqrtf((float)(1 + indeg[i]));
    }
    if (i == 0) rowptr[NN] = NE;
}
__global__ __launch_bounds__(256) void fill_k(const int* __restrict__ src, const int* __restrict__ dst,
                                              const float* __restrict__ dinv, const int* __restrict__ rowptr,
                                              int* __restrict__ cursor, int2* __restrict__ ebn) {
    int e = blockIdx.x * 256 + threadIdx.x;
    if (e >= NE) return;
    int s = src[e], d = dst[e];
    int pos = atomicAdd(&cursor[d], 1);
    ebn[rowptr[d] + pos] = make_int2(s, __float_as_int(dinv[s] * dinv[d]));
}

// ---------------- x fp32 -> bf16 (streaming, BW-bound) ----------------
__global__ __launch_bounds__(256) void xcast_k(const float* __restrict__ x, unsigned short* __restrict__ xb) {
    long i = (long)blockIdx.x * 256 + threadIdx.x;   // 8 elems per thread
    const long total = (long)NN * 512 / 8;
    if (i >= total) return;
    float4 f0 = *(const float4*)(x + i * 8);
    float4 f1 = *(const float4*)(x + i * 8 + 4);
    short8 v;
    v[0] = (short)f2b(f0.x); v[1] = (short)f2b(f0.y);
    v[2] = (short)f2b(f0.z); v[3] = (short)f2b(f0.w);
    v[4] = (short)f2b(f1.x); v[5] = (short)f2b(f1.y);
    v[6] = (short)f2b(f1.z); v[7] = (short)f2b(f1.w);
    *(short8*)(xb + i * 8) = v;
}

// ---------------- merged weight cast+transpose (9 segments, one launch) ----------------
struct WSegs {
    const float* W[9];
    unsigned short* Wt[9];
    int K[9], N[9], Kp[9];
    int c0[10];
};
__global__ __launch_bounds__(256) void wcast_all_k(WSegs s) {
    int blk = blockIdx.x;
    #pragma unroll
    for (int g = 0; g < 9; g++) {
        if (blk >= s.c0[g] && blk < s.c0[g + 1]) {
            int idx = (blk - s.c0[g]) * 256 + threadIdx.x;
            int Kp = s.Kp[g];
            int n = idx / Kp, k = idx % Kp;
            float v = (n < s.N[g] && k < s.K[g]) ? s.W[g][(size_t)k * s.N[g] + n] : 0.0f;
            s.Wt[g][idx] = f2b(v);
        }
    }
}

// ---------------- MFMA bf16 GEMM: global_load_lds staging, dbuf LDS, 1 barrier/K-step --
// C[M x ldc](bf16) = A[M x lda](bf16) @ Wt[ldc x Kp]^T (+bias). 4 waves (2x2).
template<int BM, int BN>
__global__ __launch_bounds__(256) void gemm_mfma_k(
    const unsigned short* __restrict__ A, const unsigned short* __restrict__ Bt,
    const float* __restrict__ bias, unsigned short* __restrict__ C,
    int M, int lda, int Kp, int N, int ldc) {
    constexpr int MR = BM / 32;
    constexpr int NF = BN / 32;
    constexpr int nA = BM / 32;
    constexpr int nB = BN / 32;
    constexpr int BUFB = (BM + BN) * 128;
    __shared__ __align__(16) char lds[2 * BUFB];

    int tid = threadIdx.x;
    int lane = tid & 63, wave = tid >> 6;
    int wr = wave >> 1, wc = wave & 1;
    int lr = lane & 15, lk = lane >> 4;
    int r0 = blockIdx.x * BM, c0 = blockIdx.y * BN;

    f32x4 acc[MR][NF];
    #pragma unroll
    for (int m = 0; m < MR; m++)
        #pragma unroll
        for (int n = 0; n < NF; n++)
            acc[m][n] = (f32x4){0.f, 0.f, 0.f, 0.f};

    auto ISSUE = [&](int k0, char* buf) {
        char* AsB = buf;
        char* BsB = buf + BM * 128;
        #pragma unroll
        for (int c = 0; c < nA; c++) {
            int o = tid + c * 256;
            int row = o >> 3;
            int octg = (o & 7) ^ (row & 7);             // inverse swizzle on source
            int gr = min(r0 + row, M - 1);
            gload16(A + (size_t)gr * lda + k0 + octg * 8, AsB + o * 16);
        }
        #pragma unroll
        for (int c = 0; c < nB; c++) {
            int o = tid + c * 256;
            int row = o >> 3;
            int octg = (o & 7) ^ (row & 7);
            gload16(Bt + (size_t)(c0 + row) * Kp + k0 + octg * 8, BsB + o * 16);
        }
    };

    int nt = Kp >> 6;
    ISSUE(0, lds);
    __syncthreads();
    for (int t = 0; t < nt; t++) {
        char* cur = lds + (t & 1) * BUFB;
        if (t + 1 < nt) ISSUE((t + 1) << 6, lds + ((t + 1) & 1) * BUFB);
        char* AsB = cur;
        char* BsB = cur + BM * 128;
        #pragma unroll
        for (int kk = 0; kk < 2; kk++) {
            int kb = kk * 64 + lk * 16;
            short8 a[MR], b[NF];
            #pragma unroll
            for (int m = 0; m < MR; m++) {
                int row = wr * (BM / 2) + m * 16 + lr;
                a[m] = *(short8*)(AsB + SWZ(row * 128 + kb, row));
            }
            #pragma unroll
            for (int n = 0; n < NF; n++) {
                int row = wc * (BN / 2) + n * 16 + lr;
                b[n] = *(short8*)(BsB + SWZ(row * 128 + kb, row));
            }
            #pragma unroll
            for (int m = 0; m < MR; m++)
                #pragma unroll
                for (int n = 0; n < NF; n++)
                    acc[m][n] = __builtin_amdgcn_mfma_f32_16x16x32_bf16(a[m], b[n], acc[m][n], 0, 0, 0);
        }
        __syncthreads();
    }

    // epilogue: acc -> LDS (padded) -> coalesced short8 global writes
    constexpr int LDC = BN + 8;
    unsigned short* ldsC = (unsigned short*)lds;
    #pragma unroll
    for (int n = 0; n < NF; n++) {
        int cc = wc * (BN / 2) + n * 16 + lr;
        int gc = c0 + cc;
        float bv = (bias != nullptr && gc < N) ? bias[gc] : 0.0f;
        bool ok = gc < N;
        #pragma unroll
        for (int m = 0; m < MR; m++)
            #pragma unroll
            for (int j = 0; j < 4; j++) {
                int row = wr * (BM / 2) + m * 16 + lk * 4 + j;
                float v = ok ? acc[m][n][j] + bv : 0.0f;
                ldsC[row * LDC + cc] = f2b(v);
            }
    }
    __syncthreads();
    constexpr int CH = (BM * BN) / 2048;
    #pragma unroll
    for (int c = 0; c < CH; c++) {
        int o = tid + c * 256;
        int row = o / (BN / 8), col = (o % (BN / 8)) * 8;
        int gr = r0 + row;
        if (gr < M)
            *(short8*)(C + (size_t)gr * ldc + c0 + col) = *(short8*)(ldsC + row * LDC + col);
    }
}

// ---------------- fused GCN aggregate + combine (CSR gather, bf16) ----------------
template<int VEC> struct BV;
template<> struct BV<1> { using T = unsigned short; };
template<> struct BV<2> { using T = u16x2; };
template<> struct BV<4> { using T = u16x4; };
template<int VEC> struct FV;
template<> struct FV<1> { using T = float; };
template<> struct FV<2> { using T = f32x2; };
template<> struct FV<4> { using T = f32x4; };

// SPLIT waves per node, each covers 64*VEC contiguous cols. ld = 64*VEC*SPLIT.
template<int VEC, int SPLIT, bool OUTF32>
__global__ __launch_bounds__(256) void gather_k(
    const unsigned short* __restrict__ h, const unsigned short* __restrict__ base,
    const float* __restrict__ dinv, const float* __restrict__ bias,
    const int2* __restrict__ ebn, const int* __restrict__ rowptr,
    void* __restrict__ outraw, float alpha, int dorelu, int F) {
    constexpr int ld = 64 * VEC * SPLIT;
    int gw = (blockIdx.x * 256 + threadIdx.x) >> 6;
    int lane = threadIdx.x & 63;
    int w = gw / SPLIT;
    int colbase = (gw % SPLIT) * 64 * VEC;
    if (w >= NN) return;
    using LT = typename BV<VEC>::T;
    const int col = colbase + lane * VEC;

    float acc[VEC];
    float dn = dinv[w];
    {
        LT t = *(const LT*)(h + (size_t)w * ld + col);   // keep h cached
        const unsigned short* tu = (const unsigned short*)&t;
        #pragma unroll
        for (int v = 0; v < VEC; v++) acc[v] = b2f(tu[v]) * dn * dn;
    }
    int e = rowptr[w], end = rowptr[w + 1];
    for (; e + 8 <= end; e += 8) {
        long long q[8];
        #pragma unroll
        for (int i = 0; i < 8; i++)
            q[i] = __builtin_nontemporal_load((const long long*)(ebn + e + i));
        LT t[8];
        #pragma unroll
        for (int i = 0; i < 8; i++)
            t[i] = *(const LT*)(h + (size_t)(int)q[i] * ld + col);
        #pragma unroll
        for (int i = 0; i < 8; i++) {
            float nr = __int_as_float((int)(q[i] >> 32));
            const unsigned short* u = (const unsigned short*)&t[i];
            #pragma unroll
            for (int v = 0; v < VEC; v++) acc[v] += b2f(u[v]) * nr;
        }
    }
    for (; e + 2 <= end; e += 2) {
        long long q0 = __builtin_nontemporal_load((const long long*)(ebn + e));
        long long q1 = __builtin_nontemporal_load((const long long*)(ebn + e + 1));
        LT t0 = *(const LT*)(h + (size_t)(int)q0 * ld + col);
        LT t1 = *(const LT*)(h + (size_t)(int)q1 * ld + col);
        float n0 = __int_as_float((int)(q0 >> 32)), n1 = __int_as_float((int)(q1 >> 32));
        const unsigned short* u0 = (const unsigned short*)&t0;
        const unsigned short* u1 = (const unsigned short*)&t1;
        #pragma unroll
        for (int v = 0; v < VEC; v++) acc[v] += b2f(u0[v]) * n0 + b2f(u1[v]) * n1;
    }
    if (e < end) {
        long long q0 = __builtin_nontemporal_load((const long long*)(ebn + e));
        LT t0 = *(const LT*)(h + (size_t)(int)q0 * ld + col);
        float n0 = __int_as_float((int)(q0 >> 32));
        const unsigned short* u0 = (const unsigned short*)&t0;
        #pragma unroll
        for (int v = 0; v < VEC; v++) acc[v] += b2f(u0[v]) * n0;
    }
    LT bt = __builtin_nontemporal_load((const LT*)(base + (size_t)w * ld + col));  // read-once
    const unsigned short* bu = (const unsigned short*)&bt;
    if (OUTF32) {
        typename FV<VEC>::T ot;
        float* of = (float*)&ot;
        #pragma unroll
        for (int v = 0; v < VEC; v++) {
            int f = col + v;
            float a = acc[v] + ((f < F) ? bias[f] : 0.0f);
            if (dorelu) a = fmaxf(a, 0.0f);
            of[v] = (f < F) ? b2f(bu[v]) + alpha * a : 0.0f;
        }
        __builtin_nontemporal_store(ot, (typename FV<VEC>::T*)((float*)outraw + (size_t)w * ld + col));
    } else {
        LT ot;
        unsigned short* ou = (unsigned short*)&ot;
        #pragma unroll
        for (int v = 0; v < VEC; v++) {
            int f = col + v;
            float a = acc[v] + ((f < F) ? bias[f] : 0.0f);
            if (dorelu) a = fmaxf(a, 0.0f);
            float res = (f < F) ? b2f(bu[v]) + alpha * a : 0.0f;
            ou[v] = f2b(res);
        }
        __builtin_nontemporal_store(ot, (LT*)((unsigned short*)outraw + (size_t)w * ld + col));
    }
}

extern "C" void kernel_launch(void* const* d_in, const int* in_sizes, int n_in,
                              void* d_out, int out_size, void* d_ws, size_t ws_size,
                              hipStream_t stream) {
    const float* x   = (const float*)d_in[0];
    const int*   ei  = (const int*)d_in[1];
    const float* W1  = (const float*)d_in[2];  const float* b1  = (const float*)d_in[3];
    const float* W2  = (const float*)d_in[4];  const float* b2  = (const float*)d_in[5];
    const float* W3  = (const float*)d_in[6];  const float* b3  = (const float*)d_in[7];
    const float* Wg1 = (const float*)d_in[8];  const float* bg1 = (const float*)d_in[9];
    const float* Wg2 = (const float*)d_in[10]; const float* bg2 = (const float*)d_in[11];
    const float* Wg3 = (const float*)d_in[12]; const float* bg3 = (const float*)d_in[13];
    const float* Wg4 = (const float*)d_in[14]; const float* bg4 = (const float*)d_in[15];
    const float* Wg5 = (const float*)d_in[16]; const float* bg5 = (const float*)d_in[17];
    const float* Wg6 = (const float*)d_in[18]; const float* bg6 = (const float*)d_in[19];
    const int* srcv = ei;
    const int* dstv = ei + NE;

    float* dinv = (float*)d_ws;                               // 51200 f32
    unsigned short* xb = (unsigned short*)(dinv + 51200);     // NN x 512 bf16
    unsigned short* hA = xb + (size_t)NN * 512;               // NN x 256 bf16
    unsigned short* hB = hA + (size_t)NN * 256;
    unsigned short* hC = hB + (size_t)NN * 256;
    unsigned short* W1t  = hC + (size_t)NN * 256;  // 256x512
    unsigned short* Wg1t = W1t  + 256 * 512;       // 256x256
    unsigned short* W2t  = Wg1t + 256 * 256;       // 64x256
    unsigned short* Wg2t = W2t  + 64 * 256;        // 64x64
    unsigned short* W3t  = Wg2t + 64 * 64;         // 128x64
    unsigned short* Wg3t = W3t  + 128 * 64;        // 128x128
    unsigned short* Wg4t = Wg3t + 128 * 128;
    unsigned short* Wg5t = Wg4t + 128 * 128;
    unsigned short* Wg6t = Wg5t + 128 * 128;
    int* indeg  = (int*)(Wg6t + 128 * 128);
    int* cursor = indeg + 51200;
    int* tmp    = cursor + 51200;
    int* rowptr = tmp + 51200;                     // 51264
    int* bsum   = rowptr + 51264;
    int* boff   = bsum + 256;
    int2* ebn   = (int2*)(boff + 256);             // 400000 x 8B

    // CSR + dinv
    zero2_k<<<NBLK, 256, 0, stream>>>(indeg, cursor);
    count_k<<<(NE + 255) / 256, 256, 0, stream>>>(dstv, indeg);
    scan1_k<<<NBLK, 256, 0, stream>>>(indeg, tmp, bsum);
    scan2_k<<<1, 256, 0, stream>>>(bsum, boff);
    scan3_k<<<NBLK, 256, 0, stream>>>(tmp, indeg, boff, rowptr, dinv);
    fill_k<<<(NE + 255) / 256, 256, 0, stream>>>(srcv, dstv, dinv, rowptr, cursor, ebn);

    // x -> bf16
    xcast_k<<<(int)(((long)NN * 512 / 8 + 255) / 256), 256, 0, stream>>>(x, xb);

    // weights: one merged cast+transpose launch
    {
        WSegs s;
        const float* Ws[9] = {W1, Wg1, W2, Wg2, W3, Wg3, Wg4, Wg5, Wg6};
        unsigned short* Wts[9] = {W1t, Wg1t, W2t, Wg2t, W3t, Wg3t, Wg4t, Wg5t, Wg6t};
        int Ks[9]  = {512, 256, 256, 62, 62, 128, 128, 128, 128};
        int Ns[9]  = {256, 256, 62, 62, 128, 128, 128, 128, 128};
        int Kps[9] = {512, 256, 256, 64, 64, 128, 128, 128, 128};
        int Nps[9] = {256, 256, 64, 64, 128, 128, 128, 128, 128};
        int c = 0;
        for (int g = 0; g < 9; g++) {
            s.W[g] = Ws[g]; s.Wt[g] = Wts[g];
            s.K[g] = Ks[g]; s.N[g] = Ns[g]; s.Kp[g] = Kps[g];
            s.c0[g] = c;
            c += (Kps[g] * Nps[g]) / 256;
        }
        s.c0[9] = c;
        wcast_all_k<<<c, 256, 0, stream>>>(s);
    }

    const int GX = (NN + 63) / 64;                 // 782
    const int GG1 = (NN * 64 + 255) / 256;         // 1 wave/node
    const int GG2 = (NN * 2 * 64 + 255) / 256;     // 2 waves/node

    // L1: x1l -> hA ; h -> hB ; x1 -> hC   (ld 256)
    gemm_mfma_k<64, 128><<<dim3(GX, 2), 256, 0, stream>>>(xb, W1t, b1, hA, NN, 512, 512, 256, 256);
    gemm_mfma_k<64, 128><<<dim3(GX, 2), 256, 0, stream>>>(hA, Wg1t, nullptr, hB, NN, 256, 256, 256, 256);
    gather_k<2, 2, false><<<GG2, 256, 0, stream>>>(hB, hA, dinv, bg1, ebn, rowptr, hC, 1.0f, 1, 256);
    // L2: x2l -> hA ; h -> hB ; x2 -> hC   (ld 64)
    gemm_mfma_k<64, 64><<<dim3(GX, 1), 256, 0, stream>>>(hC, W2t, b2, hA, NN, 256, 256, 62, 64);
    gemm_mfma_k<64, 64><<<dim3(GX, 1), 256, 0, stream>>>(hA, Wg2t, nullptr, hB, NN, 64, 64, 62, 64);
    gather_k<1, 1, false><<<GG1, 256, 0, stream>>>(hB, hA, dinv, bg2, ebn, rowptr, hC, 1.0f, 1, 62);
    // L3: x3l -> hA ; h -> hB ; x3 -> hC   (ld 128)
    gemm_mfma_k<64, 64><<<dim3(GX, 2), 256, 0, stream>>>(hC, W3t, b3, hA, NN, 64, 64, 128, 128);
    gemm_mfma_k<64, 64><<<dim3(GX, 2), 256, 0, stream>>>(hA, Wg3t, nullptr, hB, NN, 128, 128, 128, 128);
    gather_k<2, 1, false><<<GG1, 256, 0, stream>>>(hB, hA, dinv, bg3, ebn, rowptr, hC, 0.5f, 1, 128);
    // L4: h -> hA ; x4 -> hB
    gemm_mfma_k<64, 64><<<dim3(GX, 2), 256, 0, stream>>>(hC, Wg4t, nullptr, hA, NN, 128, 128, 128, 128);
    gather_k<2, 1, false><<<GG1, 256, 0, stream>>>(hA, hC, dinv, bg4, ebn, rowptr, hB, 0.5f, 1, 128);
    // L5: h -> hA ; x5 -> hC
    gemm_mfma_k<64, 64><<<dim3(GX, 2), 256, 0, stream>>>(hB, Wg5t, nullptr, hA, NN, 128, 128, 128, 128);
    gather_k<2, 1, false><<<GG1, 256, 0, stream>>>(hA, hB, dinv, bg5, ebn, rowptr, hC, 0.25f, 1, 128);
    // L6: h -> hA ; x6 -> d_out (fp32)
    gemm_mfma_k<64, 64><<<dim3(GX, 2), 256, 0, stream>>>(hC, Wg6t, nullptr, hA, NN, 128, 128, 128, 128);
    gather_k<2, 1, true><<<GG1, 256, 0, stream>>>(hA, hC, dinv, bg6, ebn, rowptr, d_out, 0.25f, 0, 128);
}

// Round 9
// 404.939 us; speedup vs baseline: 1.0067x; 1.0067x over previous
//
#include <hip/hip_runtime.h>

#define NN 50000
#define NE 400000
#define NBLK 196   // ceil(NN/256)

using short8 = __attribute__((ext_vector_type(8))) short;
using f32x4  = __attribute__((ext_vector_type(4))) float;
using f32x2  = __attribute__((ext_vector_type(2))) float;
using u16x2  = __attribute__((ext_vector_type(2))) unsigned short;
using u16x4  = __attribute__((ext_vector_type(4))) unsigned short;

__device__ __forceinline__ unsigned short f2b(float f) {
    union { float f; unsigned int u; } x; x.f = f;
    unsigned int u = x.u;
    u += 0x7fffu + ((u >> 16) & 1u);   // RNE
    return (unsigned short)(u >> 16);
}
__device__ __forceinline__ float b2f(unsigned short u) {
    union { unsigned int u; float f; } x; x.u = ((unsigned int)u) << 16;
    return x.f;
}

#define SWZ(b, row) ((b) ^ (((row) & 7) << 4))

__device__ __forceinline__ void gload16(const void* g, void* l) {
    __builtin_amdgcn_global_load_lds(
        (const __attribute__((address_space(1))) void*)g,
        (__attribute__((address_space(3))) void*)l, 16, 0, 0);
}

// ---------------- CSR build ----------------
__global__ __launch_bounds__(256) void zero2_k(int* a, int* b) {
    int i = blockIdx.x * 256 + threadIdx.x;
    if (i < NN) { a[i] = 0; b[i] = 0; }
}
__global__ __launch_bounds__(256) void count_k(const int* __restrict__ dst, int* __restrict__ indeg) {
    int e = blockIdx.x * 256 + threadIdx.x;
    if (e < NE) atomicAdd(&indeg[dst[e]], 1);
}
__global__ __launch_bounds__(256) void scan1_k(const int* __restrict__ indeg, int* __restrict__ tmp,
                                               int* __restrict__ bsum) {
    __shared__ int s[256];
    int t = threadIdx.x, i = blockIdx.x * 256 + t;
    int v = (i < NN) ? indeg[i] : 0;
    s[t] = v; __syncthreads();
    for (int off = 1; off < 256; off <<= 1) {
        int x = (t >= off) ? s[t - off] : 0;
        __syncthreads();
        s[t] += x;
        __syncthreads();
    }
    if (i < NN) tmp[i] = s[t];
    if (t == 255) bsum[blockIdx.x] = s[255];
}
__global__ __launch_bounds__(256) void scan2_k(const int* __restrict__ bsum, int* __restrict__ boff) {
    __shared__ int s[256];
    int t = threadIdx.x;
    int v = (t < NBLK) ? bsum[t] : 0;
    s[t] = v; __syncthreads();
    for (int off = 1; off < 256; off <<= 1) {
        int x = (t >= off) ? s[t - off] : 0;
        __syncthreads();
        s[t] += x;
        __syncthreads();
    }
    if (t < NBLK) boff[t] = s[t] - v;   // exclusive
}
__global__ __launch_bounds__(256) void scan3_k(const int* __restrict__ tmp, const int* __restrict__ indeg,
                                               const int* __restrict__ boff, int* __restrict__ rowptr,
                                               float* __restrict__ dinv) {
    int i = blockIdx.x * 256 + threadIdx.x;
    if (i < NN) {
        rowptr[i] = tmp[i] - indeg[i] + boff[i >> 8];
        dinv[i] = rsqrtf((float)(1 + indeg[i]));
    }
    if (i == 0) rowptr[NN] = NE;
}
__global__ __launch_bounds__(256) void fill_k(const int* __restrict__ src, const int* __restrict__ dst,
                                              const float* __restrict__ dinv, const int* __restrict__ rowptr,
                                              int* __restrict__ cursor, int2* __restrict__ ebn) {
    int e = blockIdx.x * 256 + threadIdx.x;
    if (e >= NE) return;
    int s = src[e], d = dst[e];
    int pos = atomicAdd(&cursor[d], 1);
    ebn[rowptr[d] + pos] = make_int2(s, __float_as_int(dinv[s] * dinv[d]));
}

// ---------------- x fp32 -> bf16 ----------------
__global__ __launch_bounds__(256) void xcast_k(const float* __restrict__ x, unsigned short* __restrict__ xb) {
    long i = (long)blockIdx.x * 256 + threadIdx.x;
    const long total = (long)NN * 512 / 8;
    if (i >= total) return;
    float4 f0 = *(const float4*)(x + i * 8);
    float4 f1 = *(const float4*)(x + i * 8 + 4);
    short8 v;
    v[0] = (short)f2b(f0.x); v[1] = (short)f2b(f0.y);
    v[2] = (short)f2b(f0.z); v[3] = (short)f2b(f0.w);
    v[4] = (short)f2b(f1.x); v[5] = (short)f2b(f1.y);
    v[6] = (short)f2b(f1.z); v[7] = (short)f2b(f1.w);
    *(short8*)(xb + i * 8) = v;
}

// ---------------- merged weight cast+transpose ----------------
struct WSegs {
    const float* W[9];
    unsigned short* Wt[9];
    int K[9], N[9], Kp[9];
    int c0[10];
};
__global__ __launch_bounds__(256) void wcast_all_k(WSegs s) {
    int blk = blockIdx.x;
    #pragma unroll
    for (int g = 0; g < 9; g++) {
        if (blk >= s.c0[g] && blk < s.c0[g + 1]) {
            int idx = (blk - s.c0[g]) * 256 + threadIdx.x;
            int Kp = s.Kp[g];
            int n = idx / Kp, k = idx % Kp;
            float v = (n < s.N[g] && k < s.K[g]) ? s.W[g][(size_t)k * s.N[g] + n] : 0.0f;
            s.Wt[g][idx] = f2b(v);
        }
    }
}

// ---------------- MFMA bf16 GEMM (R7 config): gload_lds staging, dbuf LDS ----------------
template<int BM, int BN>
__global__ __launch_bounds__(256) void gemm_mfma_k(
    const unsigned short* __restrict__ A, const unsigned short* __restrict__ Bt,
    const float* __restrict__ bias, unsigned short* __restrict__ C,
    int M, int lda, int Kp, int N, int ldc) {
    constexpr int MR = BM / 32;
    constexpr int NF = BN / 32;
    constexpr int nA = BM / 32;
    constexpr int nB = BN / 32;
    constexpr int BUFB = (BM + BN) * 128;
    __shared__ __align__(16) char lds[2 * BUFB];

    int tid = threadIdx.x;
    int lane = tid & 63, wave = tid >> 6;
    int wr = wave >> 1, wc = wave & 1;
    int lr = lane & 15, lk = lane >> 4;
    int r0 = blockIdx.x * BM, c0 = blockIdx.y * BN;

    f32x4 acc[MR][NF];
    #pragma unroll
    for (int m = 0; m < MR; m++)
        #pragma unroll
        for (int n = 0; n < NF; n++)
            acc[m][n] = (f32x4){0.f, 0.f, 0.f, 0.f};

    auto ISSUE = [&](int k0, char* buf) {
        char* AsB = buf;
        char* BsB = buf + BM * 128;
        #pragma unroll
        for (int c = 0; c < nA; c++) {
            int o = tid + c * 256;
            int row = o >> 3;
            int octg = (o & 7) ^ (row & 7);
            int gr = min(r0 + row, M - 1);
            gload16(A + (size_t)gr * lda + k0 + octg * 8, AsB + o * 16);
        }
        #pragma unroll
        for (int c = 0; c < nB; c++) {
            int o = tid + c * 256;
            int row = o >> 3;
            int octg = (o & 7) ^ (row & 7);
            gload16(Bt + (size_t)(c0 + row) * Kp + k0 + octg * 8, BsB + o * 16);
        }
    };

    int nt = Kp >> 6;
    ISSUE(0, lds);
    __syncthreads();
    for (int t = 0; t < nt; t++) {
        char* cur = lds + (t & 1) * BUFB;
        if (t + 1 < nt) ISSUE((t + 1) << 6, lds + ((t + 1) & 1) * BUFB);
        char* AsB = cur;
        char* BsB = cur + BM * 128;
        #pragma unroll
        for (int kk = 0; kk < 2; kk++) {
            int kb = kk * 64 + lk * 16;
            short8 a[MR], b[NF];
            #pragma unroll
            for (int m = 0; m < MR; m++) {
                int row = wr * (BM / 2) + m * 16 + lr;
                a[m] = *(short8*)(AsB + SWZ(row * 128 + kb, row));
            }
            #pragma unroll
            for (int n = 0; n < NF; n++) {
                int row = wc * (BN / 2) + n * 16 + lr;
                b[n] = *(short8*)(BsB + SWZ(row * 128 + kb, row));
            }
            #pragma unroll
            for (int m = 0; m < MR; m++)
                #pragma unroll
                for (int n = 0; n < NF; n++)
                    acc[m][n] = __builtin_amdgcn_mfma_f32_16x16x32_bf16(a[m], b[n], acc[m][n], 0, 0, 0);
        }
        __syncthreads();
    }

    constexpr int LDC = BN + 8;
    unsigned short* ldsC = (unsigned short*)lds;
    #pragma unroll
    for (int n = 0; n < NF; n++) {
        int cc = wc * (BN / 2) + n * 16 + lr;
        int gc = c0 + cc;
        float bv = (bias != nullptr && gc < N) ? bias[gc] : 0.0f;
        bool ok = gc < N;
        #pragma unroll
        for (int m = 0; m < MR; m++)
            #pragma unroll
            for (int j = 0; j < 4; j++) {
                int row = wr * (BM / 2) + m * 16 + lk * 4 + j;
                float v = ok ? acc[m][n][j] + bv : 0.0f;
                ldsC[row * LDC + cc] = f2b(v);
            }
    }
    __syncthreads();
    constexpr int CH = (BM * BN) / 2048;
    #pragma unroll
    for (int c = 0; c < CH; c++) {
        int o = tid + c * 256;
        int row = o / (BN / 8), col = (o % (BN / 8)) * 8;
        int gr = r0 + row;
        if (gr < M)
            *(short8*)(C + (size_t)gr * ldc + c0 + col) = *(short8*)(ldsC + row * LDC + col);
    }
}

// ---------------- dual-node CSR gather: 2 nodes per wave, joint 4+4 edge unroll --------
template<int VEC> struct BV;
template<> struct BV<1> { using T = unsigned short; };
template<> struct BV<2> { using T = u16x2; };
template<> struct BV<4> { using T = u16x4; };
template<int VEC> struct FV;
template<> struct FV<1> { using T = float; };
template<> struct FV<2> { using T = f32x2; };
template<> struct FV<4> { using T = f32x4; };

template<int VEC, int SPLIT, bool OUTF32>
__global__ __launch_bounds__(256) void gather_k(
    const unsigned short* __restrict__ h, const unsigned short* __restrict__ base,
    const float* __restrict__ dinv, const float* __restrict__ bias,
    const int2* __restrict__ ebn, const int* __restrict__ rowptr,
    void* __restrict__ outraw, float alpha, int dorelu, int F) {
    constexpr int ld = 64 * VEC * SPLIT;
    using LT = typename BV<VEC>::T;
    int gw = (blockIdx.x * 256 + threadIdx.x) >> 6;
    int lane = threadIdx.x & 63;
    int pair = gw / SPLIT;
    int colseg = gw % SPLIT;
    int w0 = pair * 2, w1 = w0 + 1;
    if (w0 >= NN) return;
    bool has1 = (w1 < NN);
    const int col = colseg * 64 * VEC + lane * VEC;

    float acc0[VEC], acc1[VEC];
    float dn0 = dinv[w0];
    {
        LT t = *(const LT*)(h + (size_t)w0 * ld + col);
        const unsigned short* tu = (const unsigned short*)&t;
        #pragma unroll
        for (int v = 0; v < VEC; v++) acc0[v] = b2f(tu[v]) * dn0 * dn0;
    }
    if (has1) {
        float dn1 = dinv[w1];
        LT t = *(const LT*)(h + (size_t)w1 * ld + col);
        const unsigned short* tu = (const unsigned short*)&t;
        #pragma unroll
        for (int v = 0; v < VEC; v++) acc1[v] = b2f(tu[v]) * dn1 * dn1;
    } else {
        #pragma unroll
        for (int v = 0; v < VEC; v++) acc1[v] = 0.0f;
    }

    int e0 = rowptr[w0], end0 = rowptr[w0 + 1];
    int e1 = has1 ? end0 : 0, end1 = has1 ? rowptr[w1 + 1] : 0;   // CSR contiguity: rowptr[w1]==end0

    // joint phase: 8 row-loads in flight (4 per node)
    while (e0 + 4 <= end0 && e1 + 4 <= end1) {
        long long q0[4], q1[4];
        #pragma unroll
        for (int i = 0; i < 4; i++) {
            q0[i] = __builtin_nontemporal_load((const long long*)(ebn + e0 + i));
            q1[i] = __builtin_nontemporal_load((const long long*)(ebn + e1 + i));
        }
        LT t0[4], t1[4];
        #pragma unroll
        for (int i = 0; i < 4; i++) {
            t0[i] = *(const LT*)(h + (size_t)(int)q0[i] * ld + col);
            t1[i] = *(const LT*)(h + (size_t)(int)q1[i] * ld + col);
        }
        #pragma unroll
        for (int i = 0; i < 4; i++) {
            float n0 = __int_as_float((int)(q0[i] >> 32));
            float n1 = __int_as_float((int)(q1[i] >> 32));
            const unsigned short* u0 = (const unsigned short*)&t0[i];
            const unsigned short* u1 = (const unsigned short*)&t1[i];
            #pragma unroll
            for (int v = 0; v < VEC; v++) {
                acc0[v] += b2f(u0[v]) * n0;
                acc1[v] += b2f(u1[v]) * n1;
            }
        }
        e0 += 4; e1 += 4;
    }
    // drain node 0
    for (; e0 + 4 <= end0; e0 += 4) {
        long long q[4];
        #pragma unroll
        for (int i = 0; i < 4; i++) q[i] = __builtin_nontemporal_load((const long long*)(ebn + e0 + i));
        LT t[4];
        #pragma unroll
        for (int i = 0; i < 4; i++) t[i] = *(const LT*)(h + (size_t)(int)q[i] * ld + col);
        #pragma unroll
        for (int i = 0; i < 4; i++) {
            float nr = __int_as_float((int)(q[i] >> 32));
            const unsigned short* u = (const unsigned short*)&t[i];
            #pragma unroll
            for (int v = 0; v < VEC; v++) acc0[v] += b2f(u[v]) * nr;
        }
    }
    for (; e0 < end0; e0++) {
        long long q = __builtin_nontemporal_load((const long long*)(ebn + e0));
        LT t = *(const LT*)(h + (size_t)(int)q * ld + col);
        float nr = __int_as_float((int)(q >> 32));
        const unsigned short* u = (const unsigned short*)&t;
        #pragma unroll
        for (int v = 0; v < VEC; v++) acc0[v] += b2f(u[v]) * nr;
    }
    // drain node 1
    for (; e1 + 4 <= end1; e1 += 4) {
        long long q[4];
        #pragma unroll
        for (int i = 0; i < 4; i++) q[i] = __builtin_nontemporal_load((const long long*)(ebn + e1 + i));
        LT t[4];
        #pragma unroll
        for (int i = 0; i < 4; i++) t[i] = *(const LT*)(h + (size_t)(int)q[i] * ld + col);
        #pragma unroll
        for (int i = 0; i < 4; i++) {
            float nr = __int_as_float((int)(q[i] >> 32));
            const unsigned short* u = (const unsigned short*)&t[i];
            #pragma unroll
            for (int v = 0; v < VEC; v++) acc1[v] += b2f(u[v]) * nr;
        }
    }
    for (; e1 < end1; e1++) {
        long long q = __builtin_nontemporal_load((const long long*)(ebn + e1));
        LT t = *(const LT*)(h + (size_t)(int)q * ld + col);
        float nr = __int_as_float((int)(q >> 32));
        const unsigned short* u = (const unsigned short*)&t;
        #pragma unroll
        for (int v = 0; v < VEC; v++) acc1[v] += b2f(u[v]) * nr;
    }

    // finish both nodes
    #pragma unroll
    for (int nn = 0; nn < 2; nn++) {
        int w = nn ? w1 : w0;
        if (nn && !has1) break;
        float* acc = nn ? acc1 : acc0;
        LT bt = *(const LT*)(base + (size_t)w * ld + col);
        const unsigned short* bu = (const unsigned short*)&bt;
        if (OUTF32) {
            typename FV<VEC>::T ot;
            float* of = (float*)&ot;
            #pragma unroll
            for (int v = 0; v < VEC; v++) {
                int f = col + v;
                float a = acc[v] + ((f < F) ? bias[f] : 0.0f);
                if (dorelu) a = fmaxf(a, 0.0f);
                of[v] = (f < F) ? b2f(bu[v]) + alpha * a : 0.0f;
            }
            *(typename FV<VEC>::T*)((float*)outraw + (size_t)w * ld + col) = ot;
        } else {
            LT ot;
            unsigned short* ou = (unsigned short*)&ot;
            #pragma unroll
            for (int v = 0; v < VEC; v++) {
                int f = col + v;
                float a = acc[v] + ((f < F) ? bias[f] : 0.0f);
                if (dorelu) a = fmaxf(a, 0.0f);
                float res = (f < F) ? b2f(bu[v]) + alpha * a : 0.0f;
                ou[v] = f2b(res);
            }
            *(LT*)((unsigned short*)outraw + (size_t)w * ld + col) = ot;
        }
    }
}

extern "C" void kernel_launch(void* const* d_in, const int* in_sizes, int n_in,
                              void* d_out, int out_size, void* d_ws, size_t ws_size,
                              hipStream_t stream) {
    const float* x   = (const float*)d_in[0];
    const int*   ei  = (const int*)d_in[1];
    const float* W1  = (const float*)d_in[2];  const float* b1  = (const float*)d_in[3];
    const float* W2  = (const float*)d_in[4];  const float* b2  = (const float*)d_in[5];
    const float* W3  = (const float*)d_in[6];  const float* b3  = (const float*)d_in[7];
    const float* Wg1 = (const float*)d_in[8];  const float* bg1 = (const float*)d_in[9];
    const float* Wg2 = (const float*)d_in[10]; const float* bg2 = (const float*)d_in[11];
    const float* Wg3 = (const float*)d_in[12]; const float* bg3 = (const float*)d_in[13];
    const float* Wg4 = (const float*)d_in[14]; const float* bg4 = (const float*)d_in[15];
    const float* Wg5 = (const float*)d_in[16]; const float* bg5 = (const float*)d_in[17];
    const float* Wg6 = (const float*)d_in[18]; const float* bg6 = (const float*)d_in[19];
    const int* srcv = ei;
    const int* dstv = ei + NE;

    float* dinv = (float*)d_ws;
    unsigned short* xb = (unsigned short*)(dinv + 51200);
    unsigned short* hA = xb + (size_t)NN * 512;
    unsigned short* hB = hA + (size_t)NN * 256;
    unsigned short* hC = hB + (size_t)NN * 256;
    unsigned short* W1t  = hC + (size_t)NN * 256;
    unsigned short* Wg1t = W1t  + 256 * 512;
    unsigned short* W2t  = Wg1t + 256 * 256;
    unsigned short* Wg2t = W2t  + 64 * 256;
    unsigned short* W3t  = Wg2t + 64 * 64;
    unsigned short* Wg3t = W3t  + 128 * 64;
    unsigned short* Wg4t = Wg3t + 128 * 128;
    unsigned short* Wg5t = Wg4t + 128 * 128;
    unsigned short* Wg6t = Wg5t + 128 * 128;
    int* indeg  = (int*)(Wg6t + 128 * 128);
    int* cursor = indeg + 51200;
    int* tmp    = cursor + 51200;
    int* rowptr = tmp + 51200;
    int* bsum   = rowptr + 51264;
    int* boff   = bsum + 256;
    int2* ebn   = (int2*)(boff + 256);

    zero2_k<<<NBLK, 256, 0, stream>>>(indeg, cursor);
    count_k<<<(NE + 255) / 256, 256, 0, stream>>>(dstv, indeg);
    scan1_k<<<NBLK, 256, 0, stream>>>(indeg, tmp, bsum);
    scan2_k<<<1, 256, 0, stream>>>(bsum, boff);
    scan3_k<<<NBLK, 256, 0, stream>>>(tmp, indeg, boff, rowptr, dinv);
    fill_k<<<(NE + 255) / 256, 256, 0, stream>>>(srcv, dstv, dinv, rowptr, cursor, ebn);

    xcast_k<<<(int)(((long)NN * 512 / 8 + 255) / 256), 256, 0, stream>>>(x, xb);

    {
        WSegs s;
        const float* Ws[9] = {W1, Wg1, W2, Wg2, W3, Wg3, Wg4, Wg5, Wg6};
        unsigned short* Wts[9] = {W1t, Wg1t, W2t, Wg2t, W3t, Wg3t, Wg4t, Wg5t, Wg6t};
        int Ks[9]  = {512, 256, 256, 62, 62, 128, 128, 128, 128};
        int Ns[9]  = {256, 256, 62, 62, 128, 128, 128, 128, 128};
        int Kps[9] = {512, 256, 256, 64, 64, 128, 128, 128, 128};
        int Nps[9] = {256, 256, 64, 64, 128, 128, 128, 128, 128};
        int c = 0;
        for (int g = 0; g < 9; g++) {
            s.W[g] = Ws[g]; s.Wt[g] = Wts[g];
            s.K[g] = Ks[g]; s.N[g] = Ns[g]; s.Kp[g] = Kps[g];
            s.c0[g] = c;
            c += (Kps[g] * Nps[g]) / 256;
        }
        s.c0[9] = c;
        wcast_all_k<<<c, 256, 0, stream>>>(s);
    }

    const int GX = (NN + 63) / 64;                         // 782
    const int NPAIR = (NN + 1) / 2;                        // 25000
    auto gwaves = [&](int split) { return (NPAIR * split * 64 + 255) / 256; };

    // L1: x1l -> hA ; h -> hB ; x1 -> hC   (ld 256)
    gemm_mfma_k<64, 128><<<dim3(GX, 2), 256, 0, stream>>>(xb, W1t, b1, hA, NN, 512, 512, 256, 256);
    gemm_mfma_k<64, 128><<<dim3(GX, 2), 256, 0, stream>>>(hA, Wg1t, nullptr, hB, NN, 256, 256, 256, 256);
    gather_k<4, 1, false><<<gwaves(1), 256, 0, stream>>>(hB, hA, dinv, bg1, ebn, rowptr, hC, 1.0f, 1, 256);
    // L2: x2l -> hA ; h -> hB ; x2 -> hC   (ld 64)
    gemm_mfma_k<64, 64><<<dim3(GX, 1), 256, 0, stream>>>(hC, W2t, b2, hA, NN, 256, 256, 62, 64);
    gemm_mfma_k<64, 64><<<dim3(GX, 1), 256, 0, stream>>>(hA, Wg2t, nullptr, hB, NN, 64, 64, 62, 64);
    gather_k<1, 1, false><<<gwaves(1), 256, 0, stream>>>(hB, hA, dinv, bg2, ebn, rowptr, hC, 1.0f, 1, 62);
    // L3: x3l -> hA ; h -> hB ; x3 -> hC   (ld 128)
    gemm_mfma_k<64, 128><<<dim3(GX, 1), 256, 0, stream>>>(hC, W3t, b3, hA, NN, 64, 64, 128, 128);
    gemm_mfma_k<64, 128><<<dim3(GX, 1), 256, 0, stream>>>(hA, Wg3t, nullptr, hB, NN, 128, 128, 128, 128);
    gather_k<2, 1, false><<<gwaves(1), 256, 0, stream>>>(hB, hA, dinv, bg3, ebn, rowptr, hC, 0.5f, 1, 128);
    // L4: h -> hA ; x4 -> hB
    gemm_mfma_k<64, 128><<<dim3(GX, 1), 256, 0, stream>>>(hC, Wg4t, nullptr, hA, NN, 128, 128, 128, 128);
    gather_k<2, 1, false><<<gwaves(1), 256, 0, stream>>>(hA, hC, dinv, bg4, ebn, rowptr, hB, 0.5f, 1, 128);
    // L5: h -> hA ; x5 -> hC
    gemm_mfma_k<64, 128><<<dim3(GX, 1), 256, 0, stream>>>(hB, Wg5t, nullptr, hA, NN, 128, 128, 128, 128);
    gather_k<2, 1, false><<<gwaves(1), 256, 0, stream>>>(hA, hB, dinv, bg5, ebn, rowptr, hC, 0.25f, 1, 128);
    // L6: h -> hA ; x6 -> d_out (fp32)
    gemm_mfma_k<64, 128><<<dim3(GX, 1), 256, 0, stream>>>(hC, Wg6t, nullptr, hA, NN, 128, 128, 128, 128);
    gather_k<2, 1, true><<<gwaves(1), 256, 0, stream>>>(hA, hC, dinv, bg6, ebn, rowptr, d_out, 0.25f, 0, 128);
}

// Round 10
// 401.996 us; speedup vs baseline: 1.0140x; 1.0073x over previous
//
#include <hip/hip_runtime.h>

#define NN 50000
#define NE 400000
#define NBLK 196   // ceil(NN/256)

using short8 = __attribute__((ext_vector_type(8))) short;
using f32x4  = __attribute__((ext_vector_type(4))) float;
using f32x2  = __attribute__((ext_vector_type(2))) float;
using u16x2  = __attribute__((ext_vector_type(2))) unsigned short;
using u16x4  = __attribute__((ext_vector_type(4))) unsigned short;

__device__ __forceinline__ unsigned short f2b(float f) {
    union { float f; unsigned int u; } x; x.f = f;
    unsigned int u = x.u;
    u += 0x7fffu + ((u >> 16) & 1u);   // RNE
    return (unsigned short)(u >> 16);
}
__device__ __forceinline__ float b2f(unsigned short u) {
    union { unsigned int u; float f; } x; x.u = ((unsigned int)u) << 16;
    return x.f;
}

#define SWZ(b, row) ((b) ^ (((row) & 7) << 4))

__device__ __forceinline__ void gload16(const void* g, void* l) {
    __builtin_amdgcn_global_load_lds(
        (const __attribute__((address_space(1))) void*)g,
        (__attribute__((address_space(3))) void*)l, 16, 0, 0);
}

// ---------------- CSR build ----------------
__global__ __launch_bounds__(256) void zero2_k(int* a, int* b) {
    int i = blockIdx.x * 256 + threadIdx.x;
    if (i < NN) { a[i] = 0; b[i] = 0; }
}
__global__ __launch_bounds__(256) void count_k(const int* __restrict__ dst, int* __restrict__ indeg) {
    int e = blockIdx.x * 256 + threadIdx.x;
    if (e < NE) atomicAdd(&indeg[dst[e]], 1);
}
__global__ __launch_bounds__(256) void scan1_k(const int* __restrict__ indeg, int* __restrict__ tmp,
                                               int* __restrict__ bsum) {
    __shared__ int s[256];
    int t = threadIdx.x, i = blockIdx.x * 256 + t;
    int v = (i < NN) ? indeg[i] : 0;
    s[t] = v; __syncthreads();
    for (int off = 1; off < 256; off <<= 1) {
        int x = (t >= off) ? s[t - off] : 0;
        __syncthreads();
        s[t] += x;
        __syncthreads();
    }
    if (i < NN) tmp[i] = s[t];
    if (t == 255) bsum[blockIdx.x] = s[255];
}
__global__ __launch_bounds__(256) void scan2_k(const int* __restrict__ bsum, int* __restrict__ boff) {
    __shared__ int s[256];
    int t = threadIdx.x;
    int v = (t < NBLK) ? bsum[t] : 0;
    s[t] = v; __syncthreads();
    for (int off = 1; off < 256; off <<= 1) {
        int x = (t >= off) ? s[t - off] : 0;
        __syncthreads();
        s[t] += x;
        __syncthreads();
    }
    if (t < NBLK) boff[t] = s[t] - v;   // exclusive
}
__global__ __launch_bounds__(256) void scan3_k(const int* __restrict__ tmp, const int* __restrict__ indeg,
                                               const int* __restrict__ boff, int* __restrict__ rowptr,
                                               float* __restrict__ dinv) {
    int i = blockIdx.x * 256 + threadIdx.x;
    if (i < NN) {
        rowptr[i] = tmp[i] - indeg[i] + boff[i >> 8];
        dinv[i] = rsqrtf((float)(1 + indeg[i]));
    }
    if (i == 0) rowptr[NN] = NE;
}
__global__ __launch_bounds__(256) void fill_k(const int* __restrict__ src, const int* __restrict__ dst,
                                              const float* __restrict__ dinv, const int* __restrict__ rowptr,
                                              int* __restrict__ cursor, int2* __restrict__ ebn) {
    int e = blockIdx.x * 256 + threadIdx.x;
    if (e >= NE) return;
    int s = src[e], d = dst[e];
    int pos = atomicAdd(&cursor[d], 1);
    ebn[rowptr[d] + pos] = make_int2(s, __float_as_int(dinv[s] * dinv[d]));
}

// ---------------- merged weight cast+transpose ----------------
struct WSegs {
    const float* W[9];
    unsigned short* Wt[9];
    int K[9], N[9], Kp[9];
    int c0[10];
};
__global__ __launch_bounds__(256) void wcast_all_k(WSegs s) {
    int blk = blockIdx.x;
    #pragma unroll
    for (int g = 0; g < 9; g++) {
        if (blk >= s.c0[g] && blk < s.c0[g + 1]) {
            int idx = (blk - s.c0[g]) * 256 + threadIdx.x;
            int Kp = s.Kp[g];
            int n = idx / Kp, k = idx % Kp;
            float v = (n < s.N[g] && k < s.K[g]) ? s.W[g][(size_t)k * s.N[g] + n] : 0.0f;
            s.Wt[g][idx] = f2b(v);
        }
    }
}

// ---------------- MFMA bf16 GEMM ----------------
// AF32: reg-staged fp32 A (cast in kernel). !AF32: global_load_lds bf16 A.
// C[M x ldc](bf16) = A @ Wt[ldc x Kp]^T (+bias). 4 waves (2x2), dbuf LDS.
template<bool AF32, int BM, int BN>
__global__ __launch_bounds__(256) void gemm_mfma_k(
    const void* __restrict__ Araw, const unsigned short* __restrict__ Bt,
    const float* __restrict__ bias, unsigned short* __restrict__ C,
    int M, int lda, int Kp, int N, int ldc) {
    constexpr int MR = BM / 32;
    constexpr int NF = BN / 32;
    constexpr int nA = BM / 32;
    constexpr int nB = BN / 32;
    constexpr int BUFB = (BM + BN) * 128;
    __shared__ __align__(16) char lds[2 * BUFB];

    int tid = threadIdx.x;
    int lane = tid & 63, wave = tid >> 6;
    int wr = wave >> 1, wc = wave & 1;
    int lr = lane & 15, lk = lane >> 4;
    int r0 = blockIdx.x * BM, c0 = blockIdx.y * BN;

    f32x4 acc[MR][NF];
    #pragma unroll
    for (int m = 0; m < MR; m++)
        #pragma unroll
        for (int n = 0; n < NF; n++)
            acc[m][n] = (f32x4){0.f, 0.f, 0.f, 0.f};

    float4 fa0[nA], fa1[nA];
    short8 rb_[nB];

    // fp32 path: load to regs
    auto LOADF = [&](int k0) {
        #pragma unroll
        for (int c = 0; c < nA; c++) {
            int o = tid + c * 256, row = o >> 3, oct = o & 7;
            int gr = min(r0 + row, M - 1);
            const float* p = (const float*)Araw + (size_t)gr * lda + k0 + oct * 8;
            fa0[c] = *(const float4*)p;
            fa1[c] = *(const float4*)(p + 4);
        }
        #pragma unroll
        for (int c = 0; c < nB; c++) {
            int o = tid + c * 256, row = o >> 3, oct = o & 7;
            rb_[c] = *(const short8*)(Bt + (size_t)(c0 + row) * Kp + k0 + oct * 8);
        }
    };
    auto STOREF = [&](char* buf) {
        char* AsB = buf;
        char* BsB = buf + BM * 128;
        #pragma unroll
        for (int c = 0; c < nA; c++) {
            int o = tid + c * 256, row = o >> 3, oct = o & 7;
            short8 v;
            v[0] = (short)f2b(fa0[c].x); v[1] = (short)f2b(fa0[c].y);
            v[2] = (short)f2b(fa0[c].z); v[3] = (short)f2b(fa0[c].w);
            v[4] = (short)f2b(fa1[c].x); v[5] = (short)f2b(fa1[c].y);
            v[6] = (short)f2b(fa1[c].z); v[7] = (short)f2b(fa1[c].w);
            *(short8*)(AsB + SWZ(row * 128 + oct * 16, row)) = v;
        }
        #pragma unroll
        for (int c = 0; c < nB; c++) {
            int o = tid + c * 256, row = o >> 3, oct = o & 7;
            *(short8*)(BsB + SWZ(row * 128 + oct * 16, row)) = rb_[c];
        }
    };
    // bf16 path: async global->LDS (linear dest, pre-swizzled source)
    auto ISSUE = [&](int k0, char* buf) {
        char* AsB = buf;
        char* BsB = buf + BM * 128;
        #pragma unroll
        for (int c = 0; c < nA; c++) {
            int o = tid + c * 256;
            int row = o >> 3;
            int octg = (o & 7) ^ (row & 7);
            int gr = min(r0 + row, M - 1);
            gload16((const unsigned short*)Araw + (size_t)gr * lda + k0 + octg * 8, AsB + o * 16);
        }
        #pragma unroll
        for (int c = 0; c < nB; c++) {
            int o = tid + c * 256;
            int row = o >> 3;
            int octg = (o & 7) ^ (row & 7);
            gload16(Bt + (size_t)(c0 + row) * Kp + k0 + octg * 8, BsB + o * 16);
        }
    };

    int nt = Kp >> 6;
    if constexpr (AF32) {
        LOADF(0);
        STOREF(lds);
    } else {
        ISSUE(0, lds);
    }
    __syncthreads();
    for (int t = 0; t < nt; t++) {
        char* cur = lds + (t & 1) * BUFB;
        char* alt = lds + ((t + 1) & 1) * BUFB;
        if (t + 1 < nt) {
            if constexpr (AF32) LOADF((t + 1) << 6);
            else ISSUE((t + 1) << 6, alt);
        }
        char* AsB = cur;
        char* BsB = cur + BM * 128;
        #pragma unroll
        for (int kk = 0; kk < 2; kk++) {
            int kb = kk * 64 + lk * 16;
            short8 a[MR], b[NF];
            #pragma unroll
            for (int m = 0; m < MR; m++) {
                int row = wr * (BM / 2) + m * 16 + lr;
                a[m] = *(short8*)(AsB + SWZ(row * 128 + kb, row));
            }
            #pragma unroll
            for (int n = 0; n < NF; n++) {
                int row = wc * (BN / 2) + n * 16 + lr;
                b[n] = *(short8*)(BsB + SWZ(row * 128 + kb, row));
            }
            #pragma unroll
            for (int m = 0; m < MR; m++)
                #pragma unroll
                for (int n = 0; n < NF; n++)
                    acc[m][n] = __builtin_amdgcn_mfma_f32_16x16x32_bf16(a[m], b[n], acc[m][n], 0, 0, 0);
        }
        if constexpr (AF32) { if (t + 1 < nt) STOREF(alt); }
        __syncthreads();
    }

    // epilogue: acc -> LDS (padded) -> coalesced short8 global writes
    constexpr int LDC = BN + 8;
    unsigned short* ldsC = (unsigned short*)lds;
    #pragma unroll
    for (int n = 0; n < NF; n++) {
        int cc = wc * (BN / 2) + n * 16 + lr;
        int gc = c0 + cc;
        float bv = (bias != nullptr && gc < N) ? bias[gc] : 0.0f;
        bool ok = gc < N;
        #pragma unroll
        for (int m = 0; m < MR; m++)
            #pragma unroll
            for (int j = 0; j < 4; j++) {
                int row = wr * (BM / 2) + m * 16 + lk * 4 + j;
                float v = ok ? acc[m][n][j] + bv : 0.0f;
                ldsC[row * LDC + cc] = f2b(v);
            }
    }
    __syncthreads();
    constexpr int CH = (BM * BN) / 2048;
    #pragma unroll
    for (int c = 0; c < CH; c++) {
        int o = tid + c * 256;
        int row = o / (BN / 8), col = (o % (BN / 8)) * 8;
        int gr = r0 + row;
        if (gr < M)
            *(short8*)(C + (size_t)gr * ldc + c0 + col) = *(short8*)(ldsC + row * LDC + col);
    }
}

// ---------------- fused GCN aggregate + combine (CSR gather, bf16) ----------------
template<int VEC> struct BV;
template<> struct BV<1> { using T = unsigned short; };
template<> struct BV<2> { using T = u16x2; };
template<> struct BV<4> { using T = u16x4; };
template<int VEC> struct FV;
template<> struct FV<1> { using T = float; };
template<> struct FV<2> { using T = f32x2; };
template<> struct FV<4> { using T = f32x4; };

// SPLIT waves per node, each covers 64*VEC contiguous cols. ld = 64*VEC*SPLIT.
template<int VEC, int SPLIT, bool OUTF32>
__global__ __launch_bounds__(256) void gather_k(
    const unsigned short* __restrict__ h, const unsigned short* __restrict__ base,
    const float* __restrict__ dinv, const float* __restrict__ bias,
    const int2* __restrict__ ebn, const int* __restrict__ rowptr,
    void* __restrict__ outraw, float alpha, int dorelu, int F) {
    constexpr int ld = 64 * VEC * SPLIT;
    int gw = (blockIdx.x * 256 + threadIdx.x) >> 6;
    int lane = threadIdx.x & 63;
    int w = gw / SPLIT;
    int colbase = (gw % SPLIT) * 64 * VEC;
    if (w >= NN) return;
    using LT = typename BV<VEC>::T;
    const int col = colbase + lane * VEC;

    float acc[VEC];
    float dn = dinv[w];
    {
        LT t = *(const LT*)(h + (size_t)w * ld + col);
        const unsigned short* tu = (const unsigned short*)&t;
        #pragma unroll
        for (int v = 0; v < VEC; v++) acc[v] = b2f(tu[v]) * dn * dn;
    }
    int e = rowptr[w], end = rowptr[w + 1];
    for (; e + 8 <= end; e += 8) {
        long long q[8];
        #pragma unroll
        for (int i = 0; i < 8; i++)
            q[i] = __builtin_nontemporal_load((const long long*)(ebn + e + i));
        LT t[8];
        #pragma unroll
        for (int i = 0; i < 8; i++)
            t[i] = *(const LT*)(h + (size_t)(int)q[i] * ld + col);
        #pragma unroll
        for (int i = 0; i < 8; i++) {
            float nr = __int_as_float((int)(q[i] >> 32));
            const unsigned short* u = (const unsigned short*)&t[i];
            #pragma unroll
            for (int v = 0; v < VEC; v++) acc[v] += b2f(u[v]) * nr;
        }
    }
    for (; e + 2 <= end; e += 2) {
        long long q0 = __builtin_nontemporal_load((const long long*)(ebn + e));
        long long q1 = __builtin_nontemporal_load((const long long*)(ebn + e + 1));
        LT t0 = *(const LT*)(h + (size_t)(int)q0 * ld + col);
        LT t1 = *(const LT*)(h + (size_t)(int)q1 * ld + col);
        float n0 = __int_as_float((int)(q0 >> 32)), n1 = __int_as_float((int)(q1 >> 32));
        const unsigned short* u0 = (const unsigned short*)&t0;
        const unsigned short* u1 = (const unsigned short*)&t1;
        #pragma unroll
        for (int v = 0; v < VEC; v++) acc[v] += b2f(u0[v]) * n0 + b2f(u1[v]) * n1;
    }
    if (e < end) {
        long long q0 = __builtin_nontemporal_load((const long long*)(ebn + e));
        LT t0 = *(const LT*)(h + (size_t)(int)q0 * ld + col);
        float n0 = __int_as_float((int)(q0 >> 32));
        const unsigned short* u0 = (const unsigned short*)&t0;
        #pragma unroll
        for (int v = 0; v < VEC; v++) acc[v] += b2f(u0[v]) * n0;
    }
    LT bt = *(const LT*)(base + (size_t)w * ld + col);
    const unsigned short* bu = (const unsigned short*)&bt;
    if (OUTF32) {
        typename FV<VEC>::T ot;
        float* of = (float*)&ot;
        #pragma unroll
        for (int v = 0; v < VEC; v++) {
            int f = col + v;
            float a = acc[v] + ((f < F) ? bias[f] : 0.0f);
            if (dorelu) a = fmaxf(a, 0.0f);
            of[v] = (f < F) ? b2f(bu[v]) + alpha * a : 0.0f;
        }
        *(typename FV<VEC>::T*)((float*)outraw + (size_t)w * ld + col) = ot;
    } else {
        LT ot;
        unsigned short* ou = (unsigned short*)&ot;
        #pragma unroll
        for (int v = 0; v < VEC; v++) {
            int f = col + v;
            float a = acc[v] + ((f < F) ? bias[f] : 0.0f);
            if (dorelu) a = fmaxf(a, 0.0f);
            float res = (f < F) ? b2f(bu[v]) + alpha * a : 0.0f;
            ou[v] = f2b(res);
        }
        *(LT*)((unsigned short*)outraw + (size_t)w * ld + col) = ot;
    }
}

extern "C" void kernel_launch(void* const* d_in, const int* in_sizes, int n_in,
                              void* d_out, int out_size, void* d_ws, size_t ws_size,
                              hipStream_t stream) {
    const float* x   = (const float*)d_in[0];
    const int*   ei  = (const int*)d_in[1];
    const float* W1  = (const float*)d_in[2];  const float* b1  = (const float*)d_in[3];
    const float* W2  = (const float*)d_in[4];  const float* b2  = (const float*)d_in[5];
    const float* W3  = (const float*)d_in[6];  const float* b3  = (const float*)d_in[7];
    const float* Wg1 = (const float*)d_in[8];  const float* bg1 = (const float*)d_in[9];
    const float* Wg2 = (const float*)d_in[10]; const float* bg2 = (const float*)d_in[11];
    const float* Wg3 = (const float*)d_in[12]; const float* bg3 = (const float*)d_in[13];
    const float* Wg4 = (const float*)d_in[14]; const float* bg4 = (const float*)d_in[15];
    const float* Wg5 = (const float*)d_in[16]; const float* bg5 = (const float*)d_in[17];
    const float* Wg6 = (const float*)d_in[18]; const float* bg6 = (const float*)d_in[19];
    const int* srcv = ei;
    const int* dstv = ei + NE;

    float* dinv = (float*)d_ws;
    unsigned short* hA = (unsigned short*)(dinv + 51200);   // NN x 256 bf16
    unsigned short* hB = hA + (size_t)NN * 256;
    unsigned short* hC = hB + (size_t)NN * 256;
    unsigned short* W1t  = hC + (size_t)NN * 256;
    unsigned short* Wg1t = W1t  + 256 * 512;
    unsigned short* W2t  = Wg1t + 256 * 256;
    unsigned short* Wg2t = W2t  + 64 * 256;
    unsigned short* W3t  = Wg2t + 64 * 64;
    unsigned short* Wg3t = W3t  + 128 * 64;
    unsigned short* Wg4t = Wg3t + 128 * 128;
    unsigned short* Wg5t = Wg4t + 128 * 128;
    unsigned short* Wg6t = Wg5t + 128 * 128;
    int* indeg  = (int*)(Wg6t + 128 * 128);
    int* cursor = indeg + 51200;
    int* tmp    = cursor + 51200;
    int* rowptr = tmp + 51200;
    int* bsum   = rowptr + 51264;
    int* boff   = bsum + 256;
    int2* ebn   = (int2*)(boff + 256);

    zero2_k<<<NBLK, 256, 0, stream>>>(indeg, cursor);
    count_k<<<(NE + 255) / 256, 256, 0, stream>>>(dstv, indeg);
    scan1_k<<<NBLK, 256, 0, stream>>>(indeg, tmp, bsum);
    scan2_k<<<1, 256, 0, stream>>>(bsum, boff);
    scan3_k<<<NBLK, 256, 0, stream>>>(tmp, indeg, boff, rowptr, dinv);
    fill_k<<<(NE + 255) / 256, 256, 0, stream>>>(srcv, dstv, dinv, rowptr, cursor, ebn);

    {
        WSegs s;
        const float* Ws[9] = {W1, Wg1, W2, Wg2, W3, Wg3, Wg4, Wg5, Wg6};
        unsigned short* Wts[9] = {W1t, Wg1t, W2t, Wg2t, W3t, Wg3t, Wg4t, Wg5t, Wg6t};
        int Ks[9]  = {512, 256, 256, 62, 62, 128, 128, 128, 128};
        int Ns[9]  = {256, 256, 62, 62, 128, 128, 128, 128, 128};
        int Kps[9] = {512, 256, 256, 64, 64, 128, 128, 128, 128};
        int Nps[9] = {256, 256, 64, 64, 128, 128, 128, 128, 128};
        int c = 0;
        for (int g = 0; g < 9; g++) {
            s.W[g] = Ws[g]; s.Wt[g] = Wts[g];
            s.K[g] = Ks[g]; s.N[g] = Ns[g]; s.Kp[g] = Kps[g];
            s.c0[g] = c;
            c += (Kps[g] * Nps[g]) / 256;
        }
        s.c0[9] = c;
        wcast_all_k<<<c, 256, 0, stream>>>(s);
    }

    const int GX = (NN + 63) / 64;          // 782
    const int GG1 = (NN * 64 + 255) / 256;  // 1 wave/node
    const int GG2 = (NN * 2 * 64 + 255) / 256;

    // L1: x1l -> hA ; h -> hB ; x1 -> hC   (ld 256)
    gemm_mfma_k<true, 64, 128><<<dim3(GX, 2), 256, 0, stream>>>(x, W1t, b1, hA, NN, 512, 512, 256, 256);
    gemm_mfma_k<false, 64, 128><<<dim3(GX, 2), 256, 0, stream>>>(hA, Wg1t, nullptr, hB, NN, 256, 256, 256, 256);
    gather_k<2, 2, false><<<GG2, 256, 0, stream>>>(hB, hA, dinv, bg1, ebn, rowptr, hC, 1.0f, 1, 256);
    // L2: x2l -> hA ; h -> hB ; x2 -> hC   (ld 64)
    gemm_mfma_k<false, 64, 64><<<dim3(GX, 1), 256, 0, stream>>>(hC, W2t, b2, hA, NN, 256, 256, 62, 64);
    gemm_mfma_k<false, 64, 64><<<dim3(GX, 1), 256, 0, stream>>>(hA, Wg2t, nullptr, hB, NN, 64, 64, 62, 64);
    gather_k<1, 1, false><<<GG1, 256, 0, stream>>>(hB, hA, dinv, bg2, ebn, rowptr, hC, 1.0f, 1, 62);
    // L3: x3l -> hA ; h -> hB ; x3 -> hC   (ld 128)
    gemm_mfma_k<false, 64, 128><<<dim3(GX, 1), 256, 0, stream>>>(hC, W3t, b3, hA, NN, 64, 64, 128, 128);
    gemm_mfma_k<false, 64, 128><<<dim3(GX, 1), 256, 0, stream>>>(hA, Wg3t, nullptr, hB, NN, 128, 128, 128, 128);
    gather_k<2, 1, false><<<GG1, 256, 0, stream>>>(hB, hA, dinv, bg3, ebn, rowptr, hC, 0.5f, 1, 128);
    // L4: h -> hA ; x4 -> hB
    gemm_mfma_k<false, 64, 128><<<dim3(GX, 1), 256, 0, stream>>>(hC, Wg4t, nullptr, hA, NN, 128, 128, 128, 128);
    gather_k<2, 1, false><<<GG1, 256, 0, stream>>>(hA, hC, dinv, bg4, ebn, rowptr, hB, 0.5f, 1, 128);
    // L5: h -> hA ; x5 -> hC
    gemm_mfma_k<false, 64, 128><<<dim3(GX, 1), 256, 0, stream>>>(hB, Wg5t, nullptr, hA, NN, 128, 128, 128, 128);
    gather_k<2, 1, false><<<GG1, 256, 0, stream>>>(hA, hB, dinv, bg5, ebn, rowptr, hC, 0.25f, 1, 128);
    // L6: h -> hA ; x6 -> d_out (fp32)
    gemm_mfma_k<false, 64, 128><<<dim3(GX, 1), 256, 0, stream>>>(hC, Wg6t, nullptr, hA, NN, 128, 128, 128, 128);
    gather_k<2, 1, true><<<GG1, 256, 0, stream>>>(hA, hC, dinv, bg6, ebn, rowptr, d_out, 0.25f, 0, 128);
}